// Round 3
// baseline (1419.447 us; speedup 1.0000x reference)
//
#include <hip/hip_runtime.h>
#include <math.h>

#define B_TOT   1024
#define S_DIM   64
#define N_DIM   256
#define UNFOLDS 12
#define EPSF    1e-8f
#define L2E     1.4426950408889634f

// Guaranteed-native transcendentals (no OCML wrappers).
#if defined(__has_builtin)
#  if __has_builtin(__builtin_amdgcn_exp2f)
#    define FEXP2(x) __builtin_amdgcn_exp2f(x)
#  endif
#  if __has_builtin(__builtin_amdgcn_rcpf)
#    define FRCP(x) __builtin_amdgcn_rcpf(x)
#  endif
#endif
#ifndef FEXP2
__device__ __forceinline__ float __fexp2_asm(float x){ float r; asm("v_exp_f32 %0, %1" : "=v"(r) : "v"(x)); return r; }
#  define FEXP2(x) __fexp2_asm(x)
#endif
#ifndef FRCP
__device__ __forceinline__ float __frcp_asm(float x){ float r; asm("v_rcp_f32 %0, %1" : "=v"(r) : "v"(x)); return r; }
#  define FRCP(x) __frcp_asm(x)
#endif

__device__ __forceinline__ float softplus_f(float x) {
    return log1pf(expf(x));
}

// Pack per-(pre,post) params as float4 {A, B, WE, WEr} with i-groups-of-4
// contiguous per j:  dst index = ((i>>2)*N + j)*4 + (i&3).
// sigmoid(sigma*(v-mu)) = 1/(1+exp2(A*v+B)), A=-L2E*sigma, B=L2E*sigma*mu.
__global__ void ltc_precompute(const float* __restrict__ gleak, const float* __restrict__ vleak,
                               const float* __restrict__ cm,    const float* __restrict__ w,
                               const float* __restrict__ sigma, const float* __restrict__ mu,
                               const float* __restrict__ erev,
                               const float* __restrict__ sw,    const float* __restrict__ ssig,
                               const float* __restrict__ smu,   const float* __restrict__ serev,
                               const float* __restrict__ mask,  const float* __restrict__ smask,
                               float4* __restrict__ pb4, float4* __restrict__ sb4,
                               float4* __restrict__ pj)
{
    const int idx = blockIdx.x * blockDim.x + threadIdx.x;
    if (idx < N_DIM * N_DIM) {
        const int i = idx >> 8, jj = idx & (N_DIM - 1);
        float we = softplus_f(w[idx]) * mask[idx];
        float sg = sigma[idx];
        float4 o;
        o.x = -L2E * sg;
        o.y =  L2E * sg * mu[idx];
        o.z =  we;
        o.w =  we * erev[idx];
        pb4[(((i >> 2) * N_DIM) + jj) * 4 + (i & 3)] = o;
    }
    if (idx < S_DIM * N_DIM) {
        const int s = idx >> 8, jj = idx & (N_DIM - 1);
        float we = softplus_f(sw[idx]) * smask[idx];
        float sg = ssig[idx];
        float4 o;
        o.x = -L2E * sg;
        o.y =  L2E * sg * smu[idx];
        o.z =  we;
        o.w =  we * serev[idx];
        sb4[(((s >> 2) * N_DIM) + jj) * 4 + (s & 3)] = o;
    }
    if (idx < N_DIM) {
        float g = softplus_f(gleak[idx]);
        float4 o;
        o.x = softplus_f(cm[idx]) * (float)UNFOLDS;  // cm_t
        o.y = g;
        o.z = g * vleak[idx];
        o.w = 0.0f;
        pj[idx] = o;
    }
}

// Compute 4 i-iterations (one block) for 4 batches from prefetched regs.
__device__ __forceinline__ void blk4(const float4* P, const float4* V,
                                     float4& an, float4& ad)
{
    #pragma unroll
    for (int u = 0; u < 4; ++u) {
        const float4 p = P[u], vv = V[u];
        float t0 = fmaf(p.x, vv.x, p.y);
        float t1 = fmaf(p.x, vv.y, p.y);
        float t2 = fmaf(p.x, vv.z, p.y);
        float t3 = fmaf(p.x, vv.w, p.y);
        float e0 = FEXP2(t0), e1 = FEXP2(t1), e2 = FEXP2(t2), e3 = FEXP2(t3);
        float r0 = FRCP(1.0f + e0);
        float r1 = FRCP(1.0f + e1);
        float r2 = FRCP(1.0f + e2);
        float r3 = FRCP(1.0f + e3);
        an.x = fmaf(p.w, r0, an.x); ad.x = fmaf(p.z, r0, ad.x);
        an.y = fmaf(p.w, r1, an.y); ad.y = fmaf(p.z, r1, ad.y);
        an.z = fmaf(p.w, r2, an.z); ad.z = fmaf(p.z, r2, ad.z);
        an.w = fmaf(p.w, r3, an.w); ad.w = fmaf(p.z, r3, ad.w);
    }
}

// Prefetch one block: 4 contiguous float4 params (imm offsets 0/16/32/48)
// + 4 broadcast v-values from LDS.
__device__ __forceinline__ void pre4(const float4* __restrict__ gp, const float4* vlds,
                                     int e, int ibase, float4* P, float4* V)
{
    #pragma unroll
    for (int u = 0; u < 4; ++u) {
        P[u] = gp[e + u];
        V[u] = vlds[ibase + u];
    }
}

__global__ __launch_bounds__(1024, 4)
void ltc_main(const float* __restrict__ inputs, const float* __restrict__ state,
              const float4* __restrict__ pb4, const float4* __restrict__ sb4,
              const float4* __restrict__ pj, float* __restrict__ out)
{
    __shared__ float4 v4[N_DIM];        // v[i], component = batch
    __shared__ float4 pnum[4][N_DIM];   // partials [q][j]
    __shared__ float4 pden[4][N_DIM];
    __shared__ float  in_lds[4][S_DIM];

    const int tid = threadIdx.x;
    const int j   = tid & (N_DIM - 1);
    const int q   = tid >> 8;
    const int b0  = blockIdx.x << 2;

    ((float*)v4)[(j << 2) + q] = state[(b0 + q) * N_DIM + j];
    if (tid < 4 * S_DIM) in_lds[tid >> 6][tid & 63] = inputs[b0 * S_DIM + tid];

    const float4 c = pj[j];
    const float cmt = c.x, gl = c.y, glv = c.z;
    const float cg  = cmt + gl + EPSF;
    __syncthreads();

    // ---- sensory pass: q covers s in [16q, 16q+16), 4 blocks of 4 ----
    float4 an = make_float4(0.f, 0.f, 0.f, 0.f);
    float4 ad = make_float4(0.f, 0.f, 0.f, 0.f);
    {
        const int sb0 = q << 2;            // first s-block
        #pragma unroll
        for (int k = 0; k < 4; ++k) {
            const int e = ((sb0 + k) * N_DIM + j) * 4;
            #pragma unroll
            for (int u = 0; u < 4; ++u) {
                const int s = (sb0 + k) * 4 + u;
                const float4 p = sb4[e + u];
                float e0 = FEXP2(fmaf(p.x, in_lds[0][s], p.y));
                float e1 = FEXP2(fmaf(p.x, in_lds[1][s], p.y));
                float e2 = FEXP2(fmaf(p.x, in_lds[2][s], p.y));
                float e3 = FEXP2(fmaf(p.x, in_lds[3][s], p.y));
                float r0 = FRCP(1.0f + e0);
                float r1 = FRCP(1.0f + e1);
                float r2 = FRCP(1.0f + e2);
                float r3 = FRCP(1.0f + e3);
                an.x = fmaf(p.w, r0, an.x); ad.x = fmaf(p.z, r0, ad.x);
                an.y = fmaf(p.w, r1, an.y); ad.y = fmaf(p.z, r1, ad.y);
                an.z = fmaf(p.w, r2, an.z); ad.z = fmaf(p.z, r2, ad.z);
                an.w = fmaf(p.w, r3, an.w); ad.w = fmaf(p.z, r3, ad.w);
            }
        }
    }
    pnum[q][j] = an; pden[q][j] = ad;
    __syncthreads();

    // all threads redundantly reduce sensory partials
    float4 sn = make_float4(0.f, 0.f, 0.f, 0.f);
    float4 sd = make_float4(0.f, 0.f, 0.f, 0.f);
    #pragma unroll
    for (int qq = 0; qq < 4; ++qq) {
        float4 a = pnum[qq][j], b = pden[qq][j];
        sn.x += a.x; sn.y += a.y; sn.z += a.z; sn.w += a.w;
        sd.x += b.x; sd.y += b.y; sd.z += b.z; sd.w += b.w;
    }
    __syncthreads();   // pnum/pden reused below

    // ---- 12 ODE unfolds, software-pipelined inner loop ----
    const int ib0  = q << 4;               // first i-block (of 4) for this q
    const int e0   = ib0 * (N_DIM * 4) + (j << 2);
    const int vb0  = q << 6;

    #pragma unroll 1
    for (int step = 0; step < UNFOLDS; ++step) {
        float4 an2 = make_float4(0.f, 0.f, 0.f, 0.f);
        float4 ad2 = make_float4(0.f, 0.f, 0.f, 0.f);

        float4 PA[4], VA[4], PB[4], VB[4];
        pre4(pb4, v4, e0, vb0, PA, VA);
        #pragma unroll
        for (int bp = 0; bp < 8; ++bp) {
            pre4(pb4, v4, e0 + (2 * bp + 1) * (N_DIM * 4), vb0 + (2 * bp + 1) * 4, PB, VB);
            blk4(PA, VA, an2, ad2);
            if (bp < 7)
                pre4(pb4, v4, e0 + (2 * bp + 2) * (N_DIM * 4), vb0 + (2 * bp + 2) * 4, PA, VA);
            blk4(PB, VB, an2, ad2);
        }

        const float4 vo = v4[j];          // read old v before partial barrier
        pnum[q][j] = an2; pden[q][j] = ad2;
        __syncthreads();

        // redundant combine in every q-group (bitwise-identical results)
        float4 tn = sn, td = sd;
        #pragma unroll
        for (int qq = 0; qq < 4; ++qq) {
            float4 a = pnum[qq][j], b = pden[qq][j];
            tn.x += a.x; tn.y += a.y; tn.z += a.z; tn.w += a.w;
            td.x += b.x; td.y += b.y; td.z += b.z; td.w += b.w;
        }
        float4 vn;
        vn.x = (fmaf(cmt, vo.x, glv) + tn.x) * FRCP(cg + td.x);
        vn.y = (fmaf(cmt, vo.y, glv) + tn.y) * FRCP(cg + td.y);
        vn.z = (fmaf(cmt, vo.z, glv) + tn.z) * FRCP(cg + td.z);
        vn.w = (fmaf(cmt, vo.w, glv) + tn.w) * FRCP(cg + td.w);
        v4[j] = vn;                       // 4 writers, identical bits — benign
        __syncthreads();
    }

    out[(b0 + q) * N_DIM + j] = ((const float*)v4)[(j << 2) + q];
}

extern "C" void kernel_launch(void* const* d_in, const int* in_sizes, int n_in,
                              void* d_out, int out_size, void* d_ws, size_t ws_size,
                              hipStream_t stream)
{
    const float* inputs = (const float*)d_in[0];
    const float* state  = (const float*)d_in[1];
    const float* gleak  = (const float*)d_in[2];
    const float* vleak  = (const float*)d_in[3];
    const float* cm     = (const float*)d_in[4];
    const float* w      = (const float*)d_in[5];
    const float* sigma  = (const float*)d_in[6];
    const float* mu     = (const float*)d_in[7];
    const float* erev   = (const float*)d_in[8];
    const float* sw     = (const float*)d_in[9];
    const float* ssig   = (const float*)d_in[10];
    const float* smu    = (const float*)d_in[11];
    const float* serev  = (const float*)d_in[12];
    const float* mask   = (const float*)d_in[13];
    const float* smask  = (const float*)d_in[14];

    float4* pb4 = (float4*)d_ws;                 // [N*N] = 1 MiB
    float4* sb4 = pb4 + N_DIM * N_DIM;           // [S*N] = 256 KiB
    float4* pj  = sb4 + S_DIM * N_DIM;           // [N]   = 4 KiB

    ltc_precompute<<<(N_DIM * N_DIM + 255) / 256, 256, 0, stream>>>(
        gleak, vleak, cm, w, sigma, mu, erev, sw, ssig, smu, serev, mask, smask,
        pb4, sb4, pj);

    ltc_main<<<B_TOT / 4, 1024, 0, stream>>>(inputs, state, pb4, sb4, pj, (float*)d_out);
}

// Round 4
// 205.907 us; speedup vs baseline: 6.8936x; 6.8936x over previous
//
#include <hip/hip_runtime.h>
#include <math.h>

#define B_TOT   1024
#define S_DIM   64
#define N_DIM   256
#define UNFOLDS 12
#define EPSF    1e-8f
#define L2E     1.4426950408889634f

// Guaranteed-native transcendentals.
#if defined(__has_builtin)
#  if __has_builtin(__builtin_amdgcn_exp2f)
#    define FEXP2(x) __builtin_amdgcn_exp2f(x)
#  endif
#  if __has_builtin(__builtin_amdgcn_rcpf)
#    define FRCP(x) __builtin_amdgcn_rcpf(x)
#  endif
#endif
#ifndef FEXP2
__device__ __forceinline__ float __fexp2_asm(float x){ float r; asm("v_exp_f32 %0, %1" : "=v"(r) : "v"(x)); return r; }
#  define FEXP2(x) __fexp2_asm(x)
#endif
#ifndef FRCP
__device__ __forceinline__ float __frcp_asm(float x){ float r; asm("v_rcp_f32 %0, %1" : "=v"(r) : "v"(x)); return r; }
#  define FRCP(x) __frcp_asm(x)
#endif

__device__ __forceinline__ float softplus_f(float x) {
    return log1pf(expf(x));
}

// Pack per-(pre,post) params as float4 {A, B, WE, WEr}, i-major / j-contiguous
// (perfectly coalesced dwordx4 per wave):
//   sigmoid(sigma*(v-mu)) = 1/(1+exp2(A*v+B)), A=-L2E*sigma, B=L2E*sigma*mu
//   WE = softplus(w)*mask, WEr = WE*erev
__global__ void ltc_precompute(const float* __restrict__ gleak, const float* __restrict__ vleak,
                               const float* __restrict__ cm,    const float* __restrict__ w,
                               const float* __restrict__ sigma, const float* __restrict__ mu,
                               const float* __restrict__ erev,
                               const float* __restrict__ sw,    const float* __restrict__ ssig,
                               const float* __restrict__ smu,   const float* __restrict__ serev,
                               const float* __restrict__ mask,  const float* __restrict__ smask,
                               float4* __restrict__ p4, float4* __restrict__ s4,
                               float4* __restrict__ pj)
{
    const int idx = blockIdx.x * blockDim.x + threadIdx.x;
    if (idx < N_DIM * N_DIM) {
        float we = softplus_f(w[idx]) * mask[idx];
        float sg = sigma[idx];
        float4 o;
        o.x = -L2E * sg;
        o.y =  L2E * sg * mu[idx];
        o.z =  we;
        o.w =  we * erev[idx];
        p4[idx] = o;
    }
    if (idx < S_DIM * N_DIM) {
        float we = softplus_f(sw[idx]) * smask[idx];
        float sg = ssig[idx];
        float4 o;
        o.x = -L2E * sg;
        o.y =  L2E * sg * smu[idx];
        o.z =  we;
        o.w =  we * serev[idx];
        s4[idx] = o;
    }
    if (idx < N_DIM) {
        float g = softplus_f(gleak[idx]);
        float4 o;
        o.x = softplus_f(cm[idx]) * (float)UNFOLDS;  // cm_t
        o.y = g;
        o.z = g * vleak[idx];
        o.w = 0.0f;
        pj[idx] = o;
    }
}

// 512 threads/block, 256 blocks (4 batches each) -> 2 blocks/CU so one block's
// barrier+combine overlaps the other's compute. j = tid&255, q = tid>>8 (0/1),
// q covers i in [128q, 128q+128). All locals are named scalars/float4 — no
// arrays (R3's array ping-pong spilled to scratch: 881 MB WRITE_SIZE).
__global__ __launch_bounds__(512, 4)
void ltc_main(const float* __restrict__ inputs, const float* __restrict__ state,
              const float4* __restrict__ p4, const float4* __restrict__ s4,
              const float4* __restrict__ pj, float* __restrict__ out)
{
    __shared__ float4 v4[N_DIM];        // v[i], component = batch
    __shared__ float4 pnum[2][N_DIM];   // partials [q][j]
    __shared__ float4 pden[2][N_DIM];
    __shared__ float  in_lds[4][S_DIM];

    const int tid = threadIdx.x;
    const int j   = tid & (N_DIM - 1);
    const int q   = tid >> 8;
    const int b0  = blockIdx.x << 2;

    // init v from state: 1024 values, 512 threads, coalesced over i
    #pragma unroll
    for (int t = tid; t < 4 * N_DIM; t += 512) {
        const int b = t >> 8, i = t & (N_DIM - 1);
        ((float*)v4)[(i << 2) + b] = state[(b0 + b) * N_DIM + i];
    }
    // stage inputs [4][64]: coalesced
    if (tid < 4 * S_DIM) in_lds[tid >> 6][tid & 63] = inputs[b0 * S_DIM + tid];

    const float4 c = pj[j];
    const float cmt = c.x, gl = c.y, glv = c.z;
    const float cg  = cmt + gl + EPSF;
    __syncthreads();

    // ---- sensory pass: q covers s in [32q, 32q+32) ----
    float4 an = make_float4(0.f, 0.f, 0.f, 0.f);
    float4 ad = make_float4(0.f, 0.f, 0.f, 0.f);
    {
        const float4* __restrict__ sr = s4 + (q << 5) * N_DIM + j;
        const int sbase = q << 5;
        #pragma unroll 8
        for (int s = 0; s < 32; ++s) {
            const float4 p = sr[s * N_DIM];
            const float i0 = in_lds[0][sbase + s];
            const float i1 = in_lds[1][sbase + s];
            const float i2 = in_lds[2][sbase + s];
            const float i3 = in_lds[3][sbase + s];
            float e0 = FEXP2(fmaf(p.x, i0, p.y));
            float e1 = FEXP2(fmaf(p.x, i1, p.y));
            float e2 = FEXP2(fmaf(p.x, i2, p.y));
            float e3 = FEXP2(fmaf(p.x, i3, p.y));
            float r0 = FRCP(1.0f + e0);
            float r1 = FRCP(1.0f + e1);
            float r2 = FRCP(1.0f + e2);
            float r3 = FRCP(1.0f + e3);
            an.x = fmaf(p.w, r0, an.x); ad.x = fmaf(p.z, r0, ad.x);
            an.y = fmaf(p.w, r1, an.y); ad.y = fmaf(p.z, r1, ad.y);
            an.z = fmaf(p.w, r2, an.z); ad.z = fmaf(p.z, r2, ad.z);
            an.w = fmaf(p.w, r3, an.w); ad.w = fmaf(p.z, r3, ad.w);
        }
    }
    pnum[q][j] = an; pden[q][j] = ad;
    __syncthreads();

    // all threads redundantly reduce sensory partials into registers
    float4 sn, sd;
    {
        const float4 a0 = pnum[0][j], a1 = pnum[1][j];
        const float4 d0 = pden[0][j], d1 = pden[1][j];
        sn = make_float4(a0.x + a1.x, a0.y + a1.y, a0.z + a1.z, a0.w + a1.w);
        sd = make_float4(d0.x + d1.x, d0.y + d1.y, d0.z + d1.z, d0.w + d1.w);
    }
    __syncthreads();   // pnum/pden reused below

    // ---- 12 ODE unfolds ----
    const float4* __restrict__ pr = p4 + (q << 7) * N_DIM + j;
    const float4* __restrict__ vr = v4 + (q << 7);

    #pragma unroll 1
    for (int step = 0; step < UNFOLDS; ++step) {
        float4 an2 = make_float4(0.f, 0.f, 0.f, 0.f);
        float4 ad2 = make_float4(0.f, 0.f, 0.f, 0.f);

        #pragma unroll 8
        for (int i = 0; i < 128; ++i) {
            const float4 p  = pr[i * N_DIM];   // coalesced dwordx4, L2-resident
            const float4 vv = vr[i];           // LDS broadcast
            float e0 = FEXP2(fmaf(p.x, vv.x, p.y));
            float e1 = FEXP2(fmaf(p.x, vv.y, p.y));
            float e2 = FEXP2(fmaf(p.x, vv.z, p.y));
            float e3 = FEXP2(fmaf(p.x, vv.w, p.y));
            float r0 = FRCP(1.0f + e0);
            float r1 = FRCP(1.0f + e1);
            float r2 = FRCP(1.0f + e2);
            float r3 = FRCP(1.0f + e3);
            an2.x = fmaf(p.w, r0, an2.x); ad2.x = fmaf(p.z, r0, ad2.x);
            an2.y = fmaf(p.w, r1, an2.y); ad2.y = fmaf(p.z, r1, ad2.y);
            an2.z = fmaf(p.w, r2, an2.z); ad2.z = fmaf(p.z, r2, ad2.z);
            an2.w = fmaf(p.w, r3, an2.w); ad2.w = fmaf(p.z, r3, ad2.w);
        }

        const float4 vo = v4[j];   // read old v BEFORE the barrier (writes only occur after it)
        pnum[q][j] = an2; pden[q][j] = ad2;
        __syncthreads();

        // redundant combine in both q-groups (bitwise-identical results)
        const float4 a0 = pnum[0][j], a1 = pnum[1][j];
        const float4 d0 = pden[0][j], d1 = pden[1][j];
        float4 tn = make_float4(sn.x + a0.x + a1.x, sn.y + a0.y + a1.y,
                                sn.z + a0.z + a1.z, sn.w + a0.w + a1.w);
        float4 td = make_float4(sd.x + d0.x + d1.x, sd.y + d0.y + d1.y,
                                sd.z + d0.z + d1.z, sd.w + d0.w + d1.w);
        float4 vn;
        vn.x = (fmaf(cmt, vo.x, glv) + tn.x) * FRCP(cg + td.x);
        vn.y = (fmaf(cmt, vo.y, glv) + tn.y) * FRCP(cg + td.y);
        vn.z = (fmaf(cmt, vo.z, glv) + tn.z) * FRCP(cg + td.z);
        vn.w = (fmaf(cmt, vo.w, glv) + tn.w) * FRCP(cg + td.w);
        v4[j] = vn;                // 2 writers, identical bits — benign
        __syncthreads();
    }

    // writeback: 1024 values, coalesced over j within each batch row
    #pragma unroll
    for (int t = tid; t < 4 * N_DIM; t += 512) {
        const int b = t >> 8, jj = t & (N_DIM - 1);
        out[(b0 + b) * N_DIM + jj] = ((const float*)v4)[(jj << 2) + b];
    }
}

extern "C" void kernel_launch(void* const* d_in, const int* in_sizes, int n_in,
                              void* d_out, int out_size, void* d_ws, size_t ws_size,
                              hipStream_t stream)
{
    const float* inputs = (const float*)d_in[0];
    const float* state  = (const float*)d_in[1];
    const float* gleak  = (const float*)d_in[2];
    const float* vleak  = (const float*)d_in[3];
    const float* cm     = (const float*)d_in[4];
    const float* w      = (const float*)d_in[5];
    const float* sigma  = (const float*)d_in[6];
    const float* mu     = (const float*)d_in[7];
    const float* erev   = (const float*)d_in[8];
    const float* sw     = (const float*)d_in[9];
    const float* ssig   = (const float*)d_in[10];
    const float* smu    = (const float*)d_in[11];
    const float* serev  = (const float*)d_in[12];
    const float* mask   = (const float*)d_in[13];
    const float* smask  = (const float*)d_in[14];

    float4* p4 = (float4*)d_ws;                 // [N*N] = 1 MiB
    float4* s4 = p4 + N_DIM * N_DIM;            // [S*N] = 256 KiB
    float4* pj = s4 + S_DIM * N_DIM;            // [N]   = 4 KiB

    ltc_precompute<<<(N_DIM * N_DIM + 255) / 256, 256, 0, stream>>>(
        gleak, vleak, cm, w, sigma, mu, erev, sw, ssig, smu, serev, mask, smask,
        p4, s4, pj);

    ltc_main<<<B_TOT / 4, 512, 0, stream>>>(inputs, state, p4, s4, pj, (float*)d_out);
}